// Round 3
// baseline (90.578 us; speedup 1.0000x reference)
//
#include <hip/hip_runtime.h>
#include <stdint.h>

// Problem constants: B=4, QL=256, CL=512, XD=ED=DIM=128, YD=16
#define Bc   4
#define QLc  256
#define CLc  512
#define Dc   128
#define YDc  16
#define NROW (Bc * QLc)     // 1024 (b,q) rows
#define RPB  4              // rows per block

// ---------------- Threefry-2x32, 20 rounds (exact JAX semantics) -------------
__device__ __forceinline__ uint32_t rotl32(uint32_t x, int d) {
  return (x << d) | (x >> (32 - d));
}

__device__ __forceinline__ void tf2x32(uint32_t k0, uint32_t k1, uint32_t x0,
                                       uint32_t x1, uint32_t& o0, uint32_t& o1) {
  const uint32_t k2 = k0 ^ k1 ^ 0x1BD11BDAu;
  uint32_t v0 = x0 + k0, v1 = x1 + k1;
  v0 += v1; v1 = rotl32(v1, 13); v1 ^= v0;
  v0 += v1; v1 = rotl32(v1, 15); v1 ^= v0;
  v0 += v1; v1 = rotl32(v1, 26); v1 ^= v0;
  v0 += v1; v1 = rotl32(v1, 6);  v1 ^= v0;
  v0 += k1; v1 += k2 + 1u;
  v0 += v1; v1 = rotl32(v1, 17); v1 ^= v0;
  v0 += v1; v1 = rotl32(v1, 29); v1 ^= v0;
  v0 += v1; v1 = rotl32(v1, 16); v1 ^= v0;
  v0 += v1; v1 = rotl32(v1, 24); v1 ^= v0;
  v0 += k2; v1 += k0 + 2u;
  v0 += v1; v1 = rotl32(v1, 13); v1 ^= v0;
  v0 += v1; v1 = rotl32(v1, 15); v1 ^= v0;
  v0 += v1; v1 = rotl32(v1, 26); v1 ^= v0;
  v0 += v1; v1 = rotl32(v1, 6);  v1 ^= v0;
  v0 += k0; v1 += k1 + 3u;
  v0 += v1; v1 = rotl32(v1, 17); v1 ^= v0;
  v0 += v1; v1 = rotl32(v1, 29); v1 ^= v0;
  v0 += v1; v1 = rotl32(v1, 16); v1 ^= v0;
  v0 += v1; v1 = rotl32(v1, 24); v1 ^= v0;
  v0 += k1; v1 += k2 + 4u;
  v0 += v1; v1 = rotl32(v1, 13); v1 ^= v0;
  v0 += v1; v1 = rotl32(v1, 15); v1 ^= v0;
  v0 += v1; v1 = rotl32(v1, 26); v1 ^= v0;
  v0 += v1; v1 = rotl32(v1, 6);  v1 ^= v0;
  v0 += k2; v1 += k0 + 5u;
  o0 = v0; o1 = v1;
}

// jax.random.key(1) -> data (0,1). Partitionable split: keys[i] = tf(key,(0,i)).
__device__ __forceinline__ void subkeys(uint32_t& ck0, uint32_t& ck1,
                                        uint32_t& ek0, uint32_t& ek1) {
  tf2x32(0u, 1u, 0u, 0u, ck0, ck1);   // kcat
  tf2x32(0u, 1u, 0u, 1u, ek0, ek1);   // keps
}

__device__ __forceinline__ uint32_t rbits(uint32_t k0, uint32_t k1, uint32_t i) {
  uint32_t o0, o1;
  tf2x32(k0, k1, 0u, i, o0, o1);
  return o0 ^ o1;
}

// JAX uniform [0,1): ((bits>>9)|0x3f800000) bitcast - 1.0
__device__ __forceinline__ float bits_to_unit(uint32_t bits) {
  return __uint_as_float((bits >> 9) | 0x3f800000u) - 1.0f;
}

// Giles single-precision erfinv (bit-exact vs ref as of round 2)
__device__ __forceinline__ float erfinv_f(float x) {
  float w = -logf((1.0f - x) * (1.0f + x));
  float p;
  if (w < 5.0f) {
    w -= 2.5f;
    p = 2.81022636e-08f;
    p = fmaf(p, w, 3.43273939e-07f);
    p = fmaf(p, w, -3.5233877e-06f);
    p = fmaf(p, w, -4.39150654e-06f);
    p = fmaf(p, w, 0.00021858087f);
    p = fmaf(p, w, -0.00125372503f);
    p = fmaf(p, w, -0.00417768164f);
    p = fmaf(p, w, 0.246640727f);
    p = fmaf(p, w, 1.50140941f);
  } else {
    w = sqrtf(w) - 3.0f;
    p = -0.000200214257f;
    p = fmaf(p, w, 0.000100950558f);
    p = fmaf(p, w, 0.00134934322f);
    p = fmaf(p, w, -0.00367342844f);
    p = fmaf(p, w, 0.00573950773f);
    p = fmaf(p, w, -0.0076224613f);
    p = fmaf(p, w, 0.00943887047f);
    p = fmaf(p, w, 1.00167406f);
    p = fmaf(p, w, 2.83297682f);
  }
  return p * x;
}

// -----------------------------------------------------------------------------
// Fully fused: 256 blocks x 256 threads, 4 (b,q) rows per block.
// Argmax is wave-local (row r <-> wave r, 8 candidates/lane + shfl_xor
// butterfly). Matvec layers register-block 2 rows per thread so every weight
// load feeds 2 FMAs (halves per-block weight L2 traffic vs round 2).
// -----------------------------------------------------------------------------
__global__ __launch_bounds__(256) void k_fused(
    const float* __restrict__ q, const float* __restrict__ f,
    const float* __restrict__ logits, const float* __restrict__ W1q,
    const float* __restrict__ W1f, const float* __restrict__ b1,
    const float* __restrict__ W2, const float* __restrict__ b2,
    const float* __restrict__ Wout, const float* __restrict__ bout,
    float* __restrict__ out) {
  const int tid  = threadIdx.x;
  const int row0 = blockIdx.x * RPB;

  __shared__ float sx[RPB][Dc];          // staged input rows (q, then f[idx])
  __shared__ float sh[RPB][Dc];          // hidden activations
  __shared__ float spart[RPB][2][32];
  __shared__ float so[RPB][32];
  __shared__ int   sc[RPB];

  uint32_t ck0, ck1, ek0, ek1;
  subkeys(ck0, ck1, ek0, ek1);

  // ---- 1. gumbel-argmax, one row per wave (wave64), 8 candidates per lane --
  {
    const int wv   = tid >> 6;           // 0..3 : row within block
    const int lane = tid & 63;
    const int row  = row0 + wv;
    float best = -3.4e38f;
    int bi = 1 << 30;
#pragma unroll
    for (int j = 0; j < 8; ++j) {
      const int c = lane + j * 64;
      const uint32_t i = (uint32_t)(row * CLc + c);    // row-major (b,q,c)
      const uint32_t bits = rbits(ck0, ck1, i);
      const float fl = bits_to_unit(bits);
      const float u = fmaxf(1.17549435e-38f, fl);      // JAX minval=tiny
      const float g = -logf(-logf(u));                 // gumbel
      const float val = g + logits[i];
      if (val > best || (val == best && c < bi)) { best = val; bi = c; }
    }
#pragma unroll
    for (int s = 32; s > 0; s >>= 1) {
      const float ov = __shfl_xor(best, s);
      const int   oi = __shfl_xor(bi, s);
      if (ov > best || (ov == best && oi < bi)) { best = ov; bi = oi; }
    }
    if (lane == 0) sc[wv] = bi;
  }

  // ---- stage q rows into LDS ----------------------------------------------
#pragma unroll
  for (int i = tid; i < RPB * Dc; i += 256)
    sx[i >> 7][i & 127] = q[(row0 + (i >> 7)) * Dc + (i & 127)];
  __syncthreads();

  // ---- 2. qp = q @ W1q : 2 rows per thread share each weight load ----------
  const int l    = tid & 127;            // output column
  const int half = tid >> 7;             // 0..1
  const int r0 = half * 2, r1 = half * 2 + 1;
  float accq0 = 0.f, accq1 = 0.f;
  for (int h = 0; h < Dc; ++h) {
    const float w = W1q[h * Dc + l];
    accq0 = fmaf(sx[r0][h], w, accq0);
    accq1 = fmaf(sx[r1][h], w, accq1);
  }
  __syncthreads();

  // ---- 3. stage selected f rows, fp = f[idx] @ W1f -------------------------
#pragma unroll
  for (int i = tid; i < RPB * Dc; i += 256) {
    const int rr = i >> 7;
    const int b = (row0 + rr) >> 8;      // QL = 256
    sx[rr][i & 127] = f[(b * CLc + sc[rr]) * Dc + (i & 127)];
  }
  __syncthreads();
  float accf0 = 0.f, accf1 = 0.f;
  for (int h = 0; h < Dc; ++h) {
    const float w = W1f[h * Dc + l];
    accf0 = fmaf(sx[r0][h], w, accf0);
    accf1 = fmaf(sx[r1][h], w, accf1);
  }

  // ---- 4. h1 = relu(qp + fp + b1) ------------------------------------------
  const float bias1 = b1[l];
  sh[r0][l] = fmaxf(accq0 + accf0 + bias1, 0.0f);
  sh[r1][l] = fmaxf(accq1 + accf1 + bias1, 0.0f);
  __syncthreads();

  // ---- 5. h2 = relu(h1 @ W2 + b2) ------------------------------------------
  const float bias2 = b2[l];
  float acc20 = bias2, acc21 = bias2;
  for (int h = 0; h < Dc; ++h) {
    const float w = W2[h * Dc + l];
    acc20 = fmaf(sh[r0][h], w, acc20);
    acc21 = fmaf(sh[r1][h], w, acc21);
  }
  __syncthreads();
  sh[r0][l] = fmaxf(acc20, 0.0f);
  sh[r1][l] = fmaxf(acc21, 0.0f);
  __syncthreads();

  // ---- 6. out = h2 @ Wout + bout (32 cols x 4 rows, split-K by 2) ----------
  {
    const int k  = tid & 31;
    const int rr = (tid >> 5) & 3;
    const int g  = tid >> 7;             // 0..1 : K-half
    float p = 0.0f;
#pragma unroll
    for (int hh = 0; hh < 64; ++hh) {
      const int h = g * 64 + hh;
      p = fmaf(sh[rr][h], Wout[h * 32 + k], p);
    }
    spart[rr][g][k] = p;
  }
  __syncthreads();
  if (tid < 128) {
    const int rr = tid >> 5, k = tid & 31;
    so[rr][k] = bout[k] + spart[rr][0][k] + spart[rr][1][k];
  }
  __syncthreads();

  // ---- 7. sample: sigma = softplus(max(-15,s)); y = mu + sigma*eps ---------
  if (tid < RPB * YDc) {
    const int rr = tid >> 4, y = tid & 15;
    const int orow = row0 + rr;
    const float mu = so[rr][y];
    const float s  = so[rr][16 + y];
    const float sm = fmaxf(-15.0f, s);
    const float sigma = fmaxf(sm, 0.0f) + log1pf(expf(-fabsf(sm)));

    const uint32_t i = (uint32_t)(orow * YDc + y);     // row-major (b,q,y)
    const uint32_t bits = rbits(ek0, ek1, i);
    const float fl = bits_to_unit(bits);
    const float lo = -0.999999940395355224609375f;     // nextafter(-1,0)
    const float prod = __fmul_rn(fl, 2.0f);
    const float u = fmaxf(lo, __fadd_rn(prod, lo));
    const float eps = 1.4142135623730951f * erfinv_f(u);
    out[orow * YDc + y] = mu + sigma * eps;
  }
}

// -----------------------------------------------------------------------------
extern "C" void kernel_launch(void* const* d_in, const int* in_sizes, int n_in,
                              void* d_out, int out_size, void* d_ws, size_t ws_size,
                              hipStream_t stream) {
  const float* q      = (const float*)d_in[0];
  const float* f      = (const float*)d_in[1];
  const float* logits = (const float*)d_in[2];
  const float* W1q    = (const float*)d_in[3];
  const float* W1f    = (const float*)d_in[4];
  const float* b1     = (const float*)d_in[5];
  const float* W2     = (const float*)d_in[6];
  const float* b2     = (const float*)d_in[7];
  const float* Wout   = (const float*)d_in[8];
  const float* bout   = (const float*)d_in[9];
  float* out = (float*)d_out;

  k_fused<<<dim3(NROW / RPB), dim3(256), 0, stream>>>(
      q, f, logits, W1q, W1f, b1, W2, b2, Wout, bout, out);
}

// Round 4
// 85.327 us; speedup vs baseline: 1.0615x; 1.0615x over previous
//
#include <hip/hip_runtime.h>
#include <stdint.h>

// Problem constants: B=4, QL=256, CL=512, XD=ED=DIM=128, YD=16
#define Bc   4
#define QLc  256
#define CLc  512
#define Dc   128
#define YDc  16
#define NROW (Bc * QLc)     // 1024 (b,q) rows

// ---------------- Threefry-2x32, 20 rounds (exact JAX semantics) -------------
__device__ __forceinline__ uint32_t rotl32(uint32_t x, int d) {
  return (x << d) | (x >> (32 - d));
}

__device__ __forceinline__ void tf2x32(uint32_t k0, uint32_t k1, uint32_t x0,
                                       uint32_t x1, uint32_t& o0, uint32_t& o1) {
  const uint32_t k2 = k0 ^ k1 ^ 0x1BD11BDAu;
  uint32_t v0 = x0 + k0, v1 = x1 + k1;
  v0 += v1; v1 = rotl32(v1, 13); v1 ^= v0;
  v0 += v1; v1 = rotl32(v1, 15); v1 ^= v0;
  v0 += v1; v1 = rotl32(v1, 26); v1 ^= v0;
  v0 += v1; v1 = rotl32(v1, 6);  v1 ^= v0;
  v0 += k1; v1 += k2 + 1u;
  v0 += v1; v1 = rotl32(v1, 17); v1 ^= v0;
  v0 += v1; v1 = rotl32(v1, 29); v1 ^= v0;
  v0 += v1; v1 = rotl32(v1, 16); v1 ^= v0;
  v0 += v1; v1 = rotl32(v1, 24); v1 ^= v0;
  v0 += k2; v1 += k0 + 2u;
  v0 += v1; v1 = rotl32(v1, 13); v1 ^= v0;
  v0 += v1; v1 = rotl32(v1, 15); v1 ^= v0;
  v0 += v1; v1 = rotl32(v1, 26); v1 ^= v0;
  v0 += v1; v1 = rotl32(v1, 6);  v1 ^= v0;
  v0 += k0; v1 += k1 + 3u;
  v0 += v1; v1 = rotl32(v1, 17); v1 ^= v0;
  v0 += v1; v1 = rotl32(v1, 29); v1 ^= v0;
  v0 += v1; v1 = rotl32(v1, 16); v1 ^= v0;
  v0 += v1; v1 = rotl32(v1, 24); v1 ^= v0;
  v0 += k1; v1 += k2 + 4u;
  v0 += v1; v1 = rotl32(v1, 13); v1 ^= v0;
  v0 += v1; v1 = rotl32(v1, 15); v1 ^= v0;
  v0 += v1; v1 = rotl32(v1, 26); v1 ^= v0;
  v0 += v1; v1 = rotl32(v1, 6);  v1 ^= v0;
  v0 += k2; v1 += k0 + 5u;
  o0 = v0; o1 = v1;
}

// jax.random.key(1) -> data (0,1). Partitionable split: keys[i] = tf(key,(0,i)).
__device__ __forceinline__ void subkeys(uint32_t& ck0, uint32_t& ck1,
                                        uint32_t& ek0, uint32_t& ek1) {
  tf2x32(0u, 1u, 0u, 0u, ck0, ck1);   // kcat
  tf2x32(0u, 1u, 0u, 1u, ek0, ek1);   // keps
}

__device__ __forceinline__ uint32_t rbits(uint32_t k0, uint32_t k1, uint32_t i) {
  uint32_t o0, o1;
  tf2x32(k0, k1, 0u, i, o0, o1);
  return o0 ^ o1;
}

// JAX uniform [0,1): ((bits>>9)|0x3f800000) bitcast - 1.0
__device__ __forceinline__ float bits_to_unit(uint32_t bits) {
  return __uint_as_float((bits >> 9) | 0x3f800000u) - 1.0f;
}

// Giles single-precision erfinv (bit-exact vs ref as of round 2)
__device__ __forceinline__ float erfinv_f(float x) {
  float w = -logf((1.0f - x) * (1.0f + x));
  float p;
  if (w < 5.0f) {
    w -= 2.5f;
    p = 2.81022636e-08f;
    p = fmaf(p, w, 3.43273939e-07f);
    p = fmaf(p, w, -3.5233877e-06f);
    p = fmaf(p, w, -4.39150654e-06f);
    p = fmaf(p, w, 0.00021858087f);
    p = fmaf(p, w, -0.00125372503f);
    p = fmaf(p, w, -0.00417768164f);
    p = fmaf(p, w, 0.246640727f);
    p = fmaf(p, w, 1.50140941f);
  } else {
    w = sqrtf(w) - 3.0f;
    p = -0.000200214257f;
    p = fmaf(p, w, 0.000100950558f);
    p = fmaf(p, w, 0.00134934322f);
    p = fmaf(p, w, -0.00367342844f);
    p = fmaf(p, w, 0.00573950773f);
    p = fmaf(p, w, -0.0076224613f);
    p = fmaf(p, w, 0.00943887047f);
    p = fmaf(p, w, 1.00167406f);
    p = fmaf(p, w, 2.83297682f);
  }
  return p * x;
}

// -----------------------------------------------------------------------------
// Round-2 structure (proven 84.6 us, absmax 0.0): 512 blocks x 256 threads,
// 2 rows/block (2 blocks/CU, 8 waves/CU for latency hiding). Only change:
// argmax reduction is wave-local shfl_xor + single 2-way LDS combine per row
// (total-order argmax => same idx, no numeric change).
// -----------------------------------------------------------------------------
__global__ __launch_bounds__(256) void k_fused(
    const float* __restrict__ q, const float* __restrict__ f,
    const float* __restrict__ logits, const float* __restrict__ W1q,
    const float* __restrict__ W1f, const float* __restrict__ b1,
    const float* __restrict__ W2, const float* __restrict__ b2,
    const float* __restrict__ Wout, const float* __restrict__ bout,
    float* __restrict__ out) {
  const int tid = threadIdx.x;
  const int r   = tid >> 7;            // 0..1 : which row of the pair
  const int l   = tid & 127;           // 0..127 : lane within row
  const int row = blockIdx.x * 2 + r;  // 0..1023 global (b,q) row
  const int b   = row >> 8;            // QL = 256

  __shared__ float sx[2][Dc];          // staged input row (q, then f[idx])
  __shared__ float sh[2][Dc];          // hidden activations
  __shared__ float spart[2][4][32];
  __shared__ float so[2][32];
  __shared__ float swv[4];
  __shared__ int   swi[4];
  __shared__ int   sc[2];

  // Early-issue the q element this thread owns (consumed after the argmax).
  const float qv = q[row * Dc + l];

  uint32_t ck0, ck1, ek0, ek1;
  subkeys(ck0, ck1, ek0, ek1);

  // ---- 1. gumbel-argmax over this row's 512 logits (first-max ties) --------
  // 4 candidates/thread, wave-local shfl butterfly, then 2-way combine per row.
  {
    float best = -3.4e38f;
    int bi = 1 << 30;
#pragma unroll
    for (int j = 0; j < 4; ++j) {
      const int c = l + j * 128;
      const uint32_t i = (uint32_t)(row * CLc + c);    // row-major (b,q,c)
      const uint32_t bits = rbits(ck0, ck1, i);
      const float fl = bits_to_unit(bits);
      const float u = fmaxf(1.17549435e-38f, fl);      // JAX minval=tiny
      const float g = -logf(-logf(u));                 // gumbel
      const float val = g + logits[i];
      if (val > best || (val == best && c < bi)) { best = val; bi = c; }
    }
#pragma unroll
    for (int s = 32; s > 0; s >>= 1) {
      const float ov = __shfl_xor(best, s);
      const int   oi = __shfl_xor(bi, s);
      if (ov > best || (ov == best && oi < bi)) { best = ov; bi = oi; }
    }
    const int wave = tid >> 6;
    if ((tid & 63) == 0) { swv[wave] = best; swi[wave] = bi; }
  }

  // ---- 2. qp = q_row @ W1q (thread -> output column l) ---------------------
  sx[r][l] = qv;
  __syncthreads();
  if (l == 0) {
    const float v0 = swv[r * 2], v1 = swv[r * 2 + 1];
    const int   i0 = swi[r * 2], i1 = swi[r * 2 + 1];
    sc[r] = (v1 > v0 || (v1 == v0 && i1 < i0)) ? i1 : i0;
  }
  float acc1 = 0.0f;
  for (int h = 0; h < Dc; ++h) acc1 = fmaf(sx[r][h], W1q[h * Dc + l], acc1);

  // ---- 3. fp = f_embed[b, idx] @ W1f (selected row only) -------------------
  __syncthreads();                      // sc ready; all sx reads done
  const int csel = sc[r];
  const float fv = f[(b * CLc + csel) * Dc + l];
  sx[r][l] = fv;
  __syncthreads();
  float accf = 0.0f;
  for (int h = 0; h < Dc; ++h) accf = fmaf(sx[r][h], W1f[h * Dc + l], accf);

  // ---- 4. h1 = relu(qp + fp + b1) ------------------------------------------
  sh[r][l] = fmaxf(acc1 + accf + b1[l], 0.0f);
  __syncthreads();

  // ---- 5. h2 = relu(h1 @ W2 + b2) ------------------------------------------
  float acc2 = b2[l];
  for (int h = 0; h < Dc; ++h) acc2 = fmaf(sh[r][h], W2[h * Dc + l], acc2);
  __syncthreads();
  sh[r][l] = fmaxf(acc2, 0.0f);
  __syncthreads();

  // ---- 6. out = h2 @ Wout + bout (32 cols, split-K by 4 groups of 32) ------
  {
    const int k  = tid & 31;
    const int rr = (tid >> 5) & 1;
    const int g  = tid >> 6;            // 0..3
    float p = 0.0f;
#pragma unroll
    for (int hh = 0; hh < 32; ++hh) {
      const int h = g * 32 + hh;
      p = fmaf(sh[rr][h], Wout[h * 32 + k], p);
    }
    spart[rr][g][k] = p;
  }
  __syncthreads();
  if (tid < 64) {
    const int rr = tid >> 5, k = tid & 31;
    so[rr][k] = bout[k] + spart[rr][0][k] + spart[rr][1][k] +
                spart[rr][2][k] + spart[rr][3][k];
  }
  __syncthreads();

  // ---- 7. sample: sigma = softplus(max(-15,s)); y = mu + sigma*eps ---------
  if (tid < 32) {
    const int rr = tid >> 4, y = tid & 15;
    const int orow = blockIdx.x * 2 + rr;
    const float mu = so[rr][y];
    const float s  = so[rr][16 + y];
    const float sm = fmaxf(-15.0f, s);
    const float sigma = fmaxf(sm, 0.0f) + log1pf(expf(-fabsf(sm)));

    const uint32_t i = (uint32_t)(orow * YDc + y);     // row-major (b,q,y)
    const uint32_t bits = rbits(ek0, ek1, i);
    const float fl = bits_to_unit(bits);
    const float lo = -0.999999940395355224609375f;     // nextafter(-1,0)
    const float prod = __fmul_rn(fl, 2.0f);
    const float u = fmaxf(lo, __fadd_rn(prod, lo));
    const float eps = 1.4142135623730951f * erfinv_f(u);
    out[orow * YDc + y] = mu + sigma * eps;
  }
}

// -----------------------------------------------------------------------------
extern "C" void kernel_launch(void* const* d_in, const int* in_sizes, int n_in,
                              void* d_out, int out_size, void* d_ws, size_t ws_size,
                              hipStream_t stream) {
  const float* q      = (const float*)d_in[0];
  const float* f      = (const float*)d_in[1];
  const float* logits = (const float*)d_in[2];
  const float* W1q    = (const float*)d_in[3];
  const float* W1f    = (const float*)d_in[4];
  const float* b1     = (const float*)d_in[5];
  const float* W2     = (const float*)d_in[6];
  const float* b2     = (const float*)d_in[7];
  const float* Wout   = (const float*)d_in[8];
  const float* bout   = (const float*)d_in[9];
  float* out = (float*)d_out;

  k_fused<<<dim3(NROW / 2), dim3(256), 0, stream>>>(
      q, f, logits, W1q, W1f, b1, W2, b2, Wout, bout, out);
}